// Round 3
// baseline (547.336 us; speedup 1.0000x reference)
//
#include <hip/hip_runtime.h>
#include <math.h>
#include <stdint.h>

// KWinners: per-row top-K binary mask with duty-cycle boosting.
// x: (4096, 16384) fp32, duty: (16384,) fp32, out: (4096, 16384) fp32 0/1 mask.
//
// Round-3 design: probe counting on 16-bit key prefixes, tightened.
//  - khi (top 16 bits of order-preserving key) in LDS: 32 KB.
//  - 5 compile-time probes (threshold concentrates at 1.21 +- 0.06), zero
//    atomics in the load loop; CAP=512 -> LDS ~37 KB -> 4 blocks/CU.
//  - Non-temporal x loads + mask stores (no reuse; don't thrash L2).
//  - Merged bulk-mask-write + candidate-gather sweep.
//  - Refinement loop + serial radix fallback keep it exact for ANY input.

#define N_UNITS 16384
#define K_WIN 655
#define NT 512
#define NPROBE 5
#define CAP 512

typedef float f32x4 __attribute__((ext_vector_type(4)));

// Order-preserving float -> uint map: larger float => larger key.
__device__ __forceinline__ uint32_t fkey(float f) {
    uint32_t b = __float_as_uint(f);
    uint32_t m = (uint32_t)((int32_t)b >> 31) | 0x80000000u;
    return b ^ m;
}

__global__ void boost_kernel(const float* __restrict__ duty,
                             float* __restrict__ bf, int n) {
    int i = blockIdx.x * blockDim.x + threadIdx.x;
    if (i < n) {
        const float td = 0.03997802734375f;  // 655/16384, exact in fp32
        float s = td - duty[i];              // fp32 subtract, matches ref
        bf[i] = (float)exp((double)s);       // correctly-rounded fp32 exp
    }
}

__global__ __launch_bounds__(NT, 8) void kwinners_kernel(
    const float* __restrict__ x, const float* __restrict__ bf,
    float* __restrict__ out) {
    __shared__ __align__(16) uint32_t khiw[N_UNITS / 2];  // 32 KB, 2 khi/word
    __shared__ uint32_t red[(NT / 64) * NPROBE];
    __shared__ int cglob[NPROBE];
    __shared__ uint32_t cand_idx[CAP];  // 2 KB
    __shared__ uint32_t cand_key[CAP];  // 2 KB
    __shared__ int prb[NPROBE];
    __shared__ int sc[2];

    const int tid = threadIdx.x;
    const int lane = tid & 63;
    const int w = tid >> 6;
    const int row = blockIdx.x;
    const f32x4* xrow = (const f32x4*)(x + (size_t)row * N_UNITS);
    const f32x4* bfv = (const f32x4*)bf;
    float* orow = out + (size_t)row * N_UNITS;

    if (tid == 0) sc[0] = 0;
    __syncthreads();

    // khi of probes {1.50, 1.30, 1.21, 1.12, 0.90}: (bits>>16)|0x8000.
    // Row thresholds for boosted N(0,1) concentrate at 1.21 +- 0.06 (4 sigma);
    // widest live probe interval holds ~205 elems << CAP.
    int P[NPROBE] = {0xBFC0, 0xBFA6, 0xBF9A, 0xBF8F, 0xBF66};
    int cnt[NPROBE];
#pragma unroll
    for (int p = 0; p < NPROBE; ++p) cnt[p] = 0;

    // ---- fused: nt global load -> keys -> khi to LDS + probe counting ----
#pragma unroll
    for (int j = 0; j < N_UNITS / (NT * 4); ++j) {  // 8 iters
        int i4 = tid + j * NT;
        f32x4 xv = __builtin_nontemporal_load(xrow + i4);
        f32x4 bv = bfv[i4];
        int h0 = (int)(fkey(xv.x * bv.x) >> 16);
        int h1 = (int)(fkey(xv.y * bv.y) >> 16);
        int h2 = (int)(fkey(xv.z * bv.z) >> 16);
        int h3 = (int)(fkey(xv.w * bv.w) >> 16);
        uint2 pk;
        pk.x = (uint32_t)h0 | ((uint32_t)h1 << 16);
        pk.y = (uint32_t)h2 | ((uint32_t)h3 << 16);
        ((uint2*)khiw)[i4] = pk;
#pragma unroll
        for (int p = 0; p < NPROBE; ++p)
            cnt[p] += (h0 > P[p]) + (h1 > P[p]) + (h2 > P[p]) + (h3 > P[p]);
    }

    // ---- block reduction of probe counters -> cglob ----
    auto reduce_counts = [&]() {
#pragma unroll
        for (int p = 0; p < NPROBE; ++p) {
            int v = cnt[p];
#pragma unroll
            for (int m = 32; m >= 1; m >>= 1) v += __shfl_xor(v, m, 64);
            if (lane == 0) red[w * NPROBE + p] = (uint32_t)v;
        }
        __syncthreads();
        if (tid < NPROBE) {
            int s = 0;
#pragma unroll
            for (int ww = 0; ww < NT / 64; ++ww) s += (int)red[ww * NPROBE + tid];
            cglob[tid] = s;
        }
        __syncthreads();
    };
    reduce_counts();

    // ---- bracket (lo, hi]: count(>hi) < K <= count(>lo) ----
    int lo, hi, cab, cgl;  // cab = count(>hi), cgl = count(>lo)
    {
        int j = 0;
        while (j < NPROBE && cglob[j] < K_WIN) ++j;
        if (j == 0) {
            lo = P[0]; cgl = cglob[0]; hi = 65535; cab = 0;
        } else if (j == NPROBE) {
            lo = -1; cgl = N_UNITS; hi = P[NPROBE - 1]; cab = cglob[NPROBE - 1];
        } else {
            lo = P[j]; cgl = cglob[j]; hi = P[j - 1]; cab = cglob[j - 1];
        }
    }
    int m = cgl - cab;

    // ---- refinement (exact, terminates; ~never runs on benchmark data) ----
    while (m > CAP && (hi - lo) > 1) {
        __syncthreads();
        if (tid < NPROBE)
            prb[tid] = lo + (int)(((long)(hi - lo) * (NPROBE - tid)) / (NPROBE + 1));
        __syncthreads();
#pragma unroll
        for (int p = 0; p < NPROBE; ++p) P[p] = prb[p];
#pragma unroll
        for (int p = 0; p < NPROBE; ++p) cnt[p] = 0;
        for (int j = 0; j < 4; ++j) {
            uint4 wv = ((const uint4*)khiw)[tid + j * NT];
            int h0 = (int)(wv.x & 0xFFFFu), h1 = (int)(wv.x >> 16);
            int h2 = (int)(wv.y & 0xFFFFu), h3 = (int)(wv.y >> 16);
            int h4 = (int)(wv.z & 0xFFFFu), h5 = (int)(wv.z >> 16);
            int h6 = (int)(wv.w & 0xFFFFu), h7 = (int)(wv.w >> 16);
#pragma unroll
            for (int p = 0; p < NPROBE; ++p)
                cnt[p] += (h0 > P[p]) + (h1 > P[p]) + (h2 > P[p]) + (h3 > P[p]) +
                          (h4 > P[p]) + (h5 > P[p]) + (h6 > P[p]) + (h7 > P[p]);
        }
        reduce_counts();
        int j = 0;
        while (j < NPROBE && cglob[j] < K_WIN) ++j;
        if (j == 0) {
            lo = P[0]; cgl = cglob[0];  // hi, cab unchanged
        } else if (j == NPROBE) {
            hi = P[NPROBE - 1]; cab = cglob[NPROBE - 1];  // lo, cgl unchanged
        } else {
            lo = P[j]; cgl = cglob[j]; hi = P[j - 1]; cab = cglob[j - 1];
        }
        m = cgl - cab;
    }

    // ---- merged sweep: nt bulk mask write + candidate gather ----
    for (int j = 0; j < N_UNITS / (NT * 4); ++j) {
        int q = tid + j * NT;
        uint2 wv = ((const uint2*)khiw)[q];
        int h0 = (int)(wv.x & 0xFFFFu), h1 = (int)(wv.x >> 16);
        int h2 = (int)(wv.y & 0xFFFFu), h3 = (int)(wv.y >> 16);
        f32x4 o;
        o.x = (h0 > hi) ? 1.0f : 0.0f;
        o.y = (h1 > hi) ? 1.0f : 0.0f;
        o.z = (h2 > hi) ? 1.0f : 0.0f;
        o.w = (h3 > hi) ? 1.0f : 0.0f;
        __builtin_nontemporal_store(o, ((f32x4*)orow) + q);
        int base = q * 4;
        if (h0 > lo && h0 <= hi) {
            int p = atomicAdd(&sc[0], 1);
            if (p < CAP) cand_idx[p] = (uint32_t)(base + 0);
        }
        if (h1 > lo && h1 <= hi) {
            int p = atomicAdd(&sc[0], 1);
            if (p < CAP) cand_idx[p] = (uint32_t)(base + 1);
        }
        if (h2 > lo && h2 <= hi) {
            int p = atomicAdd(&sc[0], 1);
            if (p < CAP) cand_idx[p] = (uint32_t)(base + 2);
        }
        if (h3 > lo && h3 <= hi) {
            int p = atomicAdd(&sc[0], 1);
            if (p < CAP) cand_idx[p] = (uint32_t)(base + 3);
        }
    }
    __syncthreads();  // drains nt stores (vmcnt) + publishes cand_idx/sc[0]
    const int mm = sc[0];
    const int need = K_WIN - cab;

    // ---- fetch full keys for candidates (scattered, L2/L3-hit) ----
    const float* xr = x + (size_t)row * N_UNITS;
    const int mc = (mm <= CAP) ? mm : 0;
    for (int j = tid; j < mc; j += NT) {
        int i = (int)cand_idx[j];
        cand_key[j] = fkey(xr[i] * bf[i]);
    }
    __syncthreads();

    if (mm <= CAP) {
        // ---- exact rank among candidates; scatter the `need` winners ----
        // tie-break (key desc, idx asc) = jax.lax.top_k semantics
        for (int j = tid; j < mm; j += NT) {
            uint32_t myk = cand_key[j];
            uint32_t myi = cand_idx[j];
            int r = 0;
            for (int l = 0; l < mm; ++l) {
                uint32_t lk = cand_key[l];
                r += (lk > myk) || (lk == myk && cand_idx[l] < myi);
            }
            if (r < need) orow[myi] = 1.0f;
        }
    } else if (tid == 0) {
        // Fallback (unreachable on benchmark data): > CAP ties at khi == hi.
        // Serial radix on low 16 bits of the full key; exact, index-ordered.
        uint32_t* h8 = cand_idx;  // reuse as 256-entry histogram
        for (int b = 0; b < 256; ++b) h8[b] = 0;
        for (int i = 0; i < N_UNITS; ++i) {
            int h = (int)((khiw[i >> 1] >> ((i & 1) * 16)) & 0xFFFFu);
            if (h == hi) h8[(fkey(xr[i] * bf[i]) & 0xFFFFu) >> 8]++;
        }
        int acc = 0, d1 = 0, need2 = 0;
        for (int b = 255; b >= 0; --b) {
            int c = (int)h8[b];
            if (acc + c >= need) { d1 = b; need2 = need - acc; break; }
            acc += c;
        }
        for (int b = 0; b < 256; ++b) h8[b] = 0;
        for (int i = 0; i < N_UNITS; ++i) {
            int h = (int)((khiw[i >> 1] >> ((i & 1) * 16)) & 0xFFFFu);
            if (h == hi) {
                uint32_t kl = fkey(xr[i] * bf[i]) & 0xFFFFu;
                if ((int)(kl >> 8) == d1) h8[kl & 0xFFu]++;
            }
        }
        int acc2 = 0, d2 = 0, need3 = 0;
        for (int b = 255; b >= 0; --b) {
            int c = (int)h8[b];
            if (acc2 + c >= need2) { d2 = b; need3 = need2 - acc2; break; }
            acc2 += c;
        }
        uint32_t Tlo = ((uint32_t)d1 << 8) | (uint32_t)d2;
        int r = 0;
        for (int i = 0; i < N_UNITS; ++i) {
            int h = (int)((khiw[i >> 1] >> ((i & 1) * 16)) & 0xFFFFu);
            if (h == hi) {
                uint32_t kl = fkey(xr[i] * bf[i]) & 0xFFFFu;
                if (kl > Tlo) orow[i] = 1.0f;
                else if (kl == Tlo && r < need3) { orow[i] = 1.0f; ++r; }
            }
        }
    }
}

extern "C" void kernel_launch(void* const* d_in, const int* in_sizes, int n_in,
                              void* d_out, int out_size, void* d_ws,
                              size_t ws_size, hipStream_t stream) {
    const float* x = (const float*)d_in[0];
    const float* duty = (const float*)d_in[1];
    float* out = (float*)d_out;
    float* bf = (float*)d_ws;  // 16384 floats = 64 KB scratch

    hipLaunchKernelGGL(boost_kernel, dim3(N_UNITS / 256), dim3(256), 0, stream,
                       duty, bf, N_UNITS);
    int rows = out_size / N_UNITS;  // 4096
    hipLaunchKernelGGL(kwinners_kernel, dim3(rows), dim3(NT), 0, stream, x, bf,
                       out);
}

// Round 4
// 499.235 us; speedup vs baseline: 1.0963x; 1.0963x over previous
//
#include <hip/hip_runtime.h>
#include <math.h>
#include <stdint.h>

// KWinners: per-row top-K binary mask with duty-cycle boosting.
// x: (4096, 16384) fp32, duty: (16384,) fp32, out: (4096, 16384) fp32 0/1 mask.
//
// Round-4 design: register-resident probe counting.
//  - khi (top 16 bits of order-preserving key) kept PACKED IN VGPRS
//    (32 elems/thread = 16 regs) -- no LDS key array, ~4.5 KB LDS total,
//    4 blocks/CU x 8 waves = full wave-slot occupancy.
//  - CACHED loads/stores (round-3 lesson: nt loads forfeit L3 hits on x,
//    nt stores defeat L2 write-coalescing -> 1.7x write amplification).
//  - 5 compile-time probes bracket the K-th khi; candidates (m ~ 100-200)
//    ranked exactly on full 32-bit keys, (key desc, idx asc) = lax.top_k.
//  - Refinement loop + serial fallback keep it exact for ANY input.

#define N_UNITS 16384
#define K_WIN 655
#define NT 512
#define NPROBE 5
#define CAP 512
#define ITERS (N_UNITS / (NT * 4))  // 8 f32x4 per thread

typedef float f32x4 __attribute__((ext_vector_type(4)));

// Order-preserving float -> uint map: larger float => larger key.
__device__ __forceinline__ uint32_t fkey(float f) {
    uint32_t b = __float_as_uint(f);
    uint32_t m = (uint32_t)((int32_t)b >> 31) | 0x80000000u;
    return b ^ m;
}

__global__ void boost_kernel(const float* __restrict__ duty,
                             float* __restrict__ bf, int n) {
    int i = blockIdx.x * blockDim.x + threadIdx.x;
    if (i < n) {
        const float td = 0.03997802734375f;  // 655/16384, exact in fp32
        float s = td - duty[i];              // fp32 subtract, matches ref
        bf[i] = (float)exp((double)s);       // correctly-rounded fp32 exp
    }
}

__global__ __launch_bounds__(NT, 8) void kwinners_kernel(
    const float* __restrict__ x, const float* __restrict__ bf,
    float* __restrict__ out) {
    __shared__ uint32_t red[(NT / 64) * NPROBE];
    __shared__ int cglob[NPROBE];
    __shared__ int prb[NPROBE];
    __shared__ uint32_t cand_idx[CAP];  // 2 KB
    __shared__ uint32_t cand_key[CAP];  // 2 KB
    __shared__ int sc[1];

    const int tid = threadIdx.x;
    const int lane = tid & 63;
    const int w = tid >> 6;
    const int row = blockIdx.x;
    const f32x4* xrow = (const f32x4*)(x + (size_t)row * N_UNITS);
    const f32x4* bfv = (const f32x4*)bf;
    float* orow = out + (size_t)row * N_UNITS;

    if (tid == 0) sc[0] = 0;
    __syncthreads();

    // khi of probes {1.50, 1.30, 1.21, 1.12, 0.90}: (fp32 bits >>16)|0x8000.
    // Row thresholds for boosted N(0,1) concentrate at 1.21 +- 0.06 (4 sigma);
    // widest live probe interval holds ~205 elems << CAP.
    int P[NPROBE] = {0xBFC0, 0xBFA6, 0xBF9A, 0xBF8F, 0xBF66};
    int cnt[NPROBE];
#pragma unroll
    for (int p = 0; p < NPROBE; ++p) cnt[p] = 0;
    uint32_t kh[ITERS * 2];  // packed khi, 2 per word, register-resident

    // ---- fused: cached global load -> khi to regs + probe counting ----
#pragma unroll
    for (int j = 0; j < ITERS; ++j) {
        int i4 = tid + j * NT;
        f32x4 xv = xrow[i4];
        f32x4 bv = bfv[i4];
        uint32_t h0 = fkey(xv.x * bv.x) >> 16;
        uint32_t h1 = fkey(xv.y * bv.y) >> 16;
        uint32_t h2 = fkey(xv.z * bv.z) >> 16;
        uint32_t h3 = fkey(xv.w * bv.w) >> 16;
        kh[2 * j] = h0 | (h1 << 16);
        kh[2 * j + 1] = h2 | (h3 << 16);
#pragma unroll
        for (int p = 0; p < NPROBE; ++p)
            cnt[p] += ((int)h0 > P[p]) + ((int)h1 > P[p]) + ((int)h2 > P[p]) +
                      ((int)h3 > P[p]);
    }

    // ---- block reduction of probe counters -> cglob ----
    auto reduce_counts = [&]() {
#pragma unroll
        for (int p = 0; p < NPROBE; ++p) {
            int v = cnt[p];
#pragma unroll
            for (int m = 32; m >= 1; m >>= 1) v += __shfl_xor(v, m, 64);
            if (lane == 0) red[w * NPROBE + p] = (uint32_t)v;
        }
        __syncthreads();
        if (tid < NPROBE) {
            int s = 0;
#pragma unroll
            for (int ww = 0; ww < NT / 64; ++ww) s += (int)red[ww * NPROBE + tid];
            cglob[tid] = s;
        }
        __syncthreads();
    };
    reduce_counts();

    // ---- bracket (lo, hi]: count(>hi) < K <= count(>lo) ----
    int lo, hi, cab, cgl;  // cab = count(>hi), cgl = count(>lo)
    {
        int j = 0;
        while (j < NPROBE && cglob[j] < K_WIN) ++j;
        if (j == 0) {
            lo = P[0]; cgl = cglob[0]; hi = 65535; cab = 0;
        } else if (j == NPROBE) {
            lo = -1; cgl = N_UNITS; hi = P[NPROBE - 1]; cab = cglob[NPROBE - 1];
        } else {
            lo = P[j]; cgl = cglob[j]; hi = P[j - 1]; cab = cglob[j - 1];
        }
    }
    int m = cgl - cab;

    // ---- refinement (exact, terminates; ~never runs on benchmark data) ----
    while (m > CAP && (hi - lo) > 1) {
        __syncthreads();
        if (tid < NPROBE)
            prb[tid] = lo + (int)(((long)(hi - lo) * (NPROBE - tid)) / (NPROBE + 1));
        __syncthreads();
#pragma unroll
        for (int p = 0; p < NPROBE; ++p) P[p] = prb[p];
#pragma unroll
        for (int p = 0; p < NPROBE; ++p) cnt[p] = 0;
#pragma unroll
        for (int j = 0; j < ITERS; ++j) {
            int h0 = (int)(kh[2 * j] & 0xFFFFu);
            int h1 = (int)(kh[2 * j] >> 16);
            int h2 = (int)(kh[2 * j + 1] & 0xFFFFu);
            int h3 = (int)(kh[2 * j + 1] >> 16);
#pragma unroll
            for (int p = 0; p < NPROBE; ++p)
                cnt[p] += (h0 > P[p]) + (h1 > P[p]) + (h2 > P[p]) + (h3 > P[p]);
        }
        reduce_counts();
        int j = 0;
        while (j < NPROBE && cglob[j] < K_WIN) ++j;
        if (j == 0) {
            lo = P[0]; cgl = cglob[0];  // hi, cab unchanged
        } else if (j == NPROBE) {
            hi = P[NPROBE - 1]; cab = cglob[NPROBE - 1];  // lo, cgl unchanged
        } else {
            lo = P[j]; cgl = cglob[j]; hi = P[j - 1]; cab = cglob[j - 1];
        }
        m = cgl - cab;
    }

    // ---- merged sweep: cached bulk mask write + candidate gather ----
#pragma unroll
    for (int j = 0; j < ITERS; ++j) {
        int i4 = tid + j * NT;
        int h0 = (int)(kh[2 * j] & 0xFFFFu);
        int h1 = (int)(kh[2 * j] >> 16);
        int h2 = (int)(kh[2 * j + 1] & 0xFFFFu);
        int h3 = (int)(kh[2 * j + 1] >> 16);
        f32x4 o;
        o.x = (h0 > hi) ? 1.0f : 0.0f;
        o.y = (h1 > hi) ? 1.0f : 0.0f;
        o.z = (h2 > hi) ? 1.0f : 0.0f;
        o.w = (h3 > hi) ? 1.0f : 0.0f;
        ((f32x4*)orow)[i4] = o;
        int base = i4 * 4;
        if (h0 > lo && h0 <= hi) {
            int p = atomicAdd(&sc[0], 1);
            if (p < CAP) cand_idx[p] = (uint32_t)(base + 0);
        }
        if (h1 > lo && h1 <= hi) {
            int p = atomicAdd(&sc[0], 1);
            if (p < CAP) cand_idx[p] = (uint32_t)(base + 1);
        }
        if (h2 > lo && h2 <= hi) {
            int p = atomicAdd(&sc[0], 1);
            if (p < CAP) cand_idx[p] = (uint32_t)(base + 2);
        }
        if (h3 > lo && h3 <= hi) {
            int p = atomicAdd(&sc[0], 1);
            if (p < CAP) cand_idx[p] = (uint32_t)(base + 3);
        }
    }
    __syncthreads();  // publishes cand_idx / sc[0]
    const int mm = sc[0];
    const int need = K_WIN - cab;

    // ---- fetch full keys for candidates (scattered, L2/L3-hit) ----
    const float* xr = x + (size_t)row * N_UNITS;
    const int mc = (mm <= CAP) ? mm : 0;
    for (int j = tid; j < mc; j += NT) {
        int i = (int)cand_idx[j];
        cand_key[j] = fkey(xr[i] * bf[i]);
    }
    __syncthreads();

    if (mm <= CAP) {
        // ---- exact rank among candidates; scatter the `need` winners ----
        // tie-break (key desc, idx asc) = jax.lax.top_k semantics
        for (int j = tid; j < mm; j += NT) {
            uint32_t myk = cand_key[j];
            uint32_t myi = cand_idx[j];
            int r = 0;
            for (int l = 0; l < mm; ++l) {
                uint32_t lk = cand_key[l];
                r += (lk > myk) || (lk == myk && cand_idx[l] < myi);
            }
            if (r < need) orow[myi] = 1.0f;
        }
    } else if (tid == 0) {
        // Fallback (unreachable on benchmark data): > CAP ties at khi == hi.
        // Serial radix on low 16 bits of the full key, recomputed from global;
        // exact, index-ordered.
        uint32_t* h8 = cand_idx;  // reuse as 256-entry histogram
        for (int b = 0; b < 256; ++b) h8[b] = 0;
        for (int i = 0; i < N_UNITS; ++i) {
            uint32_t k = fkey(xr[i] * bf[i]);
            if ((int)(k >> 16) == hi) h8[(k & 0xFFFFu) >> 8]++;
        }
        int acc = 0, d1 = 0, need2 = 0;
        for (int b = 255; b >= 0; --b) {
            int c = (int)h8[b];
            if (acc + c >= need) { d1 = b; need2 = need - acc; break; }
            acc += c;
        }
        for (int b = 0; b < 256; ++b) h8[b] = 0;
        for (int i = 0; i < N_UNITS; ++i) {
            uint32_t k = fkey(xr[i] * bf[i]);
            if ((int)(k >> 16) == hi && (int)((k & 0xFFFFu) >> 8) == d1)
                h8[k & 0xFFu]++;
        }
        int acc2 = 0, d2 = 0, need3 = 0;
        for (int b = 255; b >= 0; --b) {
            int c = (int)h8[b];
            if (acc2 + c >= need2) { d2 = b; need3 = need2 - acc2; break; }
            acc2 += c;
        }
        uint32_t Tlo = ((uint32_t)d1 << 8) | (uint32_t)d2;
        int r = 0;
        for (int i = 0; i < N_UNITS; ++i) {
            uint32_t k = fkey(xr[i] * bf[i]);
            if ((int)(k >> 16) == hi) {
                uint32_t kl = k & 0xFFFFu;
                if (kl > Tlo) orow[i] = 1.0f;
                else if (kl == Tlo && r < need3) { orow[i] = 1.0f; ++r; }
            }
        }
    }
}

extern "C" void kernel_launch(void* const* d_in, const int* in_sizes, int n_in,
                              void* d_out, int out_size, void* d_ws,
                              size_t ws_size, hipStream_t stream) {
    const float* x = (const float*)d_in[0];
    const float* duty = (const float*)d_in[1];
    float* out = (float*)d_out;
    float* bf = (float*)d_ws;  // 16384 floats = 64 KB scratch

    hipLaunchKernelGGL(boost_kernel, dim3(N_UNITS / 256), dim3(256), 0, stream,
                       duty, bf, N_UNITS);
    int rows = out_size / N_UNITS;  // 4096
    hipLaunchKernelGGL(kwinners_kernel, dim3(rows), dim3(NT), 0, stream, x, bf,
                       out);
}

// Round 5
// 461.848 us; speedup vs baseline: 1.1851x; 1.0810x over previous
//
#include <hip/hip_runtime.h>
#include <math.h>
#include <stdint.h>

// KWinners: per-row top-K binary mask with duty-cycle boosting.
// x: (4096, 16384) fp32, duty: (16384,) fp32, out: (4096, 16384) fp32 0/1 mask.
//
// Round-5 design: register-resident probe counting, EXACT-THRESHOLD-FIRST.
//  - khi (top 16 bits of order-preserving key) packed in VGPRs (16 words).
//  - 5 compile-time probes bracket the K-th khi; candidates ranked on full
//    32-bit keys BEFORE the bulk write; khiT = khi of the weakest winner.
//  - Bulk mask write (khi > khiT) is final for all but ~2 elems/row; the
//    few winners with khi == khiT are scattered after (round-4 lesson:
//    scattering ~150/row caused 123 MB RMW write + 78 MB fetch overhead).
//  - Cached loads/stores (round-3 lesson: nt defeats L3 reuse + write merge).
//  - Refinement loop + serial fallback keep it exact for ANY input.

#define N_UNITS 16384
#define K_WIN 655
#define NT 512
#define NPROBE 5
#define CAP 512
#define ITERS (N_UNITS / (NT * 4))  // 8 f32x4 per thread

typedef float f32x4 __attribute__((ext_vector_type(4)));

// Order-preserving float -> uint map: larger float => larger key.
__device__ __forceinline__ uint32_t fkey(float f) {
    uint32_t b = __float_as_uint(f);
    uint32_t m = (uint32_t)((int32_t)b >> 31) | 0x80000000u;
    return b ^ m;
}

__global__ void boost_kernel(const float* __restrict__ duty,
                             float* __restrict__ bf, int n) {
    int i = blockIdx.x * blockDim.x + threadIdx.x;
    if (i < n) {
        const float td = 0.03997802734375f;  // 655/16384, exact in fp32
        float s = td - duty[i];              // fp32 subtract, matches ref
        bf[i] = (float)exp((double)s);       // correctly-rounded fp32 exp
    }
}

__global__ __launch_bounds__(NT, 8) void kwinners_kernel(
    const float* __restrict__ x, const float* __restrict__ bf,
    float* __restrict__ out) {
    __shared__ uint32_t red[(NT / 64) * NPROBE];
    __shared__ int cglob[NPROBE];
    __shared__ int prb[NPROBE];
    __shared__ uint32_t cand_idx[CAP];  // 2 KB; bit31 = winner flag
    __shared__ uint32_t cand_key[CAP];  // 2 KB
    __shared__ int sc[2];               // 0: cand count, 1: khiT

    const int tid = threadIdx.x;
    const int lane = tid & 63;
    const int w = tid >> 6;
    const int row = blockIdx.x;
    const f32x4* xrow = (const f32x4*)(x + (size_t)row * N_UNITS);
    const f32x4* bfv = (const f32x4*)bf;
    float* orow = out + (size_t)row * N_UNITS;

    if (tid == 0) sc[0] = 0;
    __syncthreads();

    // khi of probes {1.50, 1.30, 1.21, 1.12, 0.90}: (fp32 bits >>16)|0x8000.
    // Row thresholds for boosted N(0,1) concentrate at 1.21 +- 0.06 (4 sigma);
    // widest live probe interval holds ~205 elems << CAP.
    int P[NPROBE] = {0xBFC0, 0xBFA6, 0xBF9A, 0xBF8F, 0xBF66};
    int cnt[NPROBE];
#pragma unroll
    for (int p = 0; p < NPROBE; ++p) cnt[p] = 0;
    uint32_t kh[ITERS * 2];  // packed khi, 2 per word, register-resident

    // ---- fused: cached global load -> khi to regs + probe counting ----
#pragma unroll
    for (int j = 0; j < ITERS; ++j) {
        int i4 = tid + j * NT;
        f32x4 xv = xrow[i4];
        f32x4 bv = bfv[i4];
        uint32_t h0 = fkey(xv.x * bv.x) >> 16;
        uint32_t h1 = fkey(xv.y * bv.y) >> 16;
        uint32_t h2 = fkey(xv.z * bv.z) >> 16;
        uint32_t h3 = fkey(xv.w * bv.w) >> 16;
        kh[2 * j] = h0 | (h1 << 16);
        kh[2 * j + 1] = h2 | (h3 << 16);
#pragma unroll
        for (int p = 0; p < NPROBE; ++p)
            cnt[p] += ((int)h0 > P[p]) + ((int)h1 > P[p]) + ((int)h2 > P[p]) +
                      ((int)h3 > P[p]);
    }

    // ---- block reduction of probe counters -> cglob ----
    auto reduce_counts = [&]() {
#pragma unroll
        for (int p = 0; p < NPROBE; ++p) {
            int v = cnt[p];
#pragma unroll
            for (int m = 32; m >= 1; m >>= 1) v += __shfl_xor(v, m, 64);
            if (lane == 0) red[w * NPROBE + p] = (uint32_t)v;
        }
        __syncthreads();
        if (tid < NPROBE) {
            int s = 0;
#pragma unroll
            for (int ww = 0; ww < NT / 64; ++ww) s += (int)red[ww * NPROBE + tid];
            cglob[tid] = s;
        }
        __syncthreads();
    };
    reduce_counts();

    // ---- bracket (lo, hi]: count(>hi) < K <= count(>lo) ----
    int lo, hi, cab, cgl;  // cab = count(>hi), cgl = count(>lo)
    {
        int j = 0;
        while (j < NPROBE && cglob[j] < K_WIN) ++j;
        if (j == 0) {
            lo = P[0]; cgl = cglob[0]; hi = 65535; cab = 0;
        } else if (j == NPROBE) {
            lo = -1; cgl = N_UNITS; hi = P[NPROBE - 1]; cab = cglob[NPROBE - 1];
        } else {
            lo = P[j]; cgl = cglob[j]; hi = P[j - 1]; cab = cglob[j - 1];
        }
    }
    int m = cgl - cab;

    // ---- refinement (exact, terminates; ~never runs on benchmark data) ----
    while (m > CAP && (hi - lo) > 1) {
        __syncthreads();
        if (tid < NPROBE)
            prb[tid] = lo + (int)(((long)(hi - lo) * (NPROBE - tid)) / (NPROBE + 1));
        __syncthreads();
#pragma unroll
        for (int p = 0; p < NPROBE; ++p) P[p] = prb[p];
#pragma unroll
        for (int p = 0; p < NPROBE; ++p) cnt[p] = 0;
#pragma unroll
        for (int j = 0; j < ITERS; ++j) {
            int h0 = (int)(kh[2 * j] & 0xFFFFu);
            int h1 = (int)(kh[2 * j] >> 16);
            int h2 = (int)(kh[2 * j + 1] & 0xFFFFu);
            int h3 = (int)(kh[2 * j + 1] >> 16);
#pragma unroll
            for (int p = 0; p < NPROBE; ++p)
                cnt[p] += (h0 > P[p]) + (h1 > P[p]) + (h2 > P[p]) + (h3 > P[p]);
        }
        reduce_counts();
        int j = 0;
        while (j < NPROBE && cglob[j] < K_WIN) ++j;
        if (j == 0) {
            lo = P[0]; cgl = cglob[0];  // hi, cab unchanged
        } else if (j == NPROBE) {
            hi = P[NPROBE - 1]; cab = cglob[NPROBE - 1];  // lo, cgl unchanged
        } else {
            lo = P[j]; cgl = cglob[j]; hi = P[j - 1]; cab = cglob[j - 1];
        }
        m = cgl - cab;
    }

    // ---- candidate gather from register khi ----
#pragma unroll
    for (int j = 0; j < ITERS; ++j) {
        int base = (tid + j * NT) * 4;
        int h0 = (int)(kh[2 * j] & 0xFFFFu);
        int h1 = (int)(kh[2 * j] >> 16);
        int h2 = (int)(kh[2 * j + 1] & 0xFFFFu);
        int h3 = (int)(kh[2 * j + 1] >> 16);
        if (h0 > lo && h0 <= hi) {
            int p = atomicAdd(&sc[0], 1);
            if (p < CAP) cand_idx[p] = (uint32_t)(base + 0);
        }
        if (h1 > lo && h1 <= hi) {
            int p = atomicAdd(&sc[0], 1);
            if (p < CAP) cand_idx[p] = (uint32_t)(base + 1);
        }
        if (h2 > lo && h2 <= hi) {
            int p = atomicAdd(&sc[0], 1);
            if (p < CAP) cand_idx[p] = (uint32_t)(base + 2);
        }
        if (h3 > lo && h3 <= hi) {
            int p = atomicAdd(&sc[0], 1);
            if (p < CAP) cand_idx[p] = (uint32_t)(base + 3);
        }
    }
    __syncthreads();
    const int mm = sc[0];
    const int need = K_WIN - cab;  // 1 <= need <= mm (when mm <= CAP)
    const float* xr = x + (size_t)row * N_UNITS;

    int khiT = hi;  // fallback boundary if candidate list overflowed
    if (mm <= CAP) {
        // ---- fetch full keys for candidates (scattered, L2/L3-hit) ----
        for (int j = tid; j < mm; j += NT) {
            int i = (int)cand_idx[j];
            cand_key[j] = fkey(xr[i] * bf[i]);
        }
        __syncthreads();
        // ---- exact rank, (key desc, idx asc) = lax.top_k; mark winners,
        //      publish khiT = khi of the weakest winner (rank need-1) ----
        for (int j = tid; j < mm; j += NT) {
            uint32_t myk = cand_key[j];
            uint32_t myi = cand_idx[j];
            int r = 0;
            for (int l = 0; l < mm; ++l) {
                uint32_t lk = cand_key[l];
                r += (lk > myk) || (lk == myk && cand_idx[l] < myi);
            }
            if (r < need) cand_idx[j] = myi | 0x80000000u;
            if (r == need - 1) sc[1] = (int)(myk >> 16);
        }
        __syncthreads();
        khiT = sc[1];
    }

    // ---- bulk mask write: khi > khiT (final for all but khi==khiT) ----
#pragma unroll
    for (int j = 0; j < ITERS; ++j) {
        int i4 = tid + j * NT;
        int h0 = (int)(kh[2 * j] & 0xFFFFu);
        int h1 = (int)(kh[2 * j] >> 16);
        int h2 = (int)(kh[2 * j + 1] & 0xFFFFu);
        int h3 = (int)(kh[2 * j + 1] >> 16);
        f32x4 o;
        o.x = (h0 > khiT) ? 1.0f : 0.0f;
        o.y = (h1 > khiT) ? 1.0f : 0.0f;
        o.z = (h2 > khiT) ? 1.0f : 0.0f;
        o.w = (h3 > khiT) ? 1.0f : 0.0f;
        ((f32x4*)orow)[i4] = o;
    }
    __syncthreads();  // bulk stores drained before boundary fix-ups

    if (mm <= CAP) {
        // ---- scatter winners at the boundary khi == khiT (~1-3 per row) ----
        for (int j = tid; j < mm; j += NT) {
            uint32_t e = cand_idx[j];
            if ((e & 0x80000000u) && (int)(cand_key[j] >> 16) == khiT)
                orow[e & 0x7FFFFFFFu] = 1.0f;
        }
    } else if (tid == 0) {
        // Fallback (unreachable on benchmark data): > CAP candidates.
        // Serial radix on low 16 bits of the full key at khi == hi; exact.
        uint32_t* h8 = cand_idx;  // reuse as 256-entry histogram
        for (int b = 0; b < 256; ++b) h8[b] = 0;
        for (int i = 0; i < N_UNITS; ++i) {
            uint32_t k = fkey(xr[i] * bf[i]);
            if ((int)(k >> 16) == hi) h8[(k & 0xFFFFu) >> 8]++;
        }
        int acc = 0, d1 = 0, need2 = 0;
        for (int b = 255; b >= 0; --b) {
            int c = (int)h8[b];
            if (acc + c >= need) { d1 = b; need2 = need - acc; break; }
            acc += c;
        }
        for (int b = 0; b < 256; ++b) h8[b] = 0;
        for (int i = 0; i < N_UNITS; ++i) {
            uint32_t k = fkey(xr[i] * bf[i]);
            if ((int)(k >> 16) == hi && (int)((k & 0xFFFFu) >> 8) == d1)
                h8[k & 0xFFu]++;
        }
        int acc2 = 0, d2 = 0, need3 = 0;
        for (int b = 255; b >= 0; --b) {
            int c = (int)h8[b];
            if (acc2 + c >= need2) { d2 = b; need3 = need2 - acc2; break; }
            acc2 += c;
        }
        uint32_t Tlo = ((uint32_t)d1 << 8) | (uint32_t)d2;
        int r = 0;
        for (int i = 0; i < N_UNITS; ++i) {
            uint32_t k = fkey(xr[i] * bf[i]);
            if ((int)(k >> 16) == hi) {
                uint32_t kl = k & 0xFFFFu;
                if (kl > Tlo) orow[i] = 1.0f;
                else if (kl == Tlo && r < need3) { orow[i] = 1.0f; ++r; }
            }
        }
    }
}

extern "C" void kernel_launch(void* const* d_in, const int* in_sizes, int n_in,
                              void* d_out, int out_size, void* d_ws,
                              size_t ws_size, hipStream_t stream) {
    const float* x = (const float*)d_in[0];
    const float* duty = (const float*)d_in[1];
    float* out = (float*)d_out;
    float* bf = (float*)d_ws;  // 16384 floats = 64 KB scratch

    hipLaunchKernelGGL(boost_kernel, dim3(N_UNITS / 256), dim3(256), 0, stream,
                       duty, bf, N_UNITS);
    int rows = out_size / N_UNITS;  // 4096
    hipLaunchKernelGGL(kwinners_kernel, dim3(rows), dim3(NT), 0, stream, x, bf,
                       out);
}